// Round 1
// baseline (522.882 us; speedup 1.0000x reference)
//
#include <hip/hip_runtime.h>
#include <hip/hip_bf16.h>

#define D 128

// ---------------- K1: z = h @ W^T  (z[i][c] = sum_k h[i][k] * W[c][k]) ---------
// 32 nodes per block, 256 threads, each thread computes 4 nodes x 4 cols.
// W staged in LDS in two 32KB halves (k 0..63, 64..127); h tile 8KB half.
// Per-thread k4 rotation ((cg+it)&15) spreads LDS bank-quads (~4-way max).
__global__ __launch_bounds__(256) void k_lin(const float* __restrict__ h,
                                             const float* __restrict__ W,
                                             float* __restrict__ z, int n) {
  __shared__ float4 Wl[128 * 16];  // [col][k4local]  32KB
  __shared__ float4 Hl[32 * 16];   // [node][k4local]  8KB
  const int tid = threadIdx.x;
  const int cg = tid & 31;   // col group: cols 4cg..4cg+3
  const int ng = tid >> 5;   // node group 0..7: nodes 4ng..4ng+3
  const int nb = blockIdx.x * 32;

  float acc[4][4];
#pragma unroll
  for (int m = 0; m < 4; ++m)
#pragma unroll
    for (int j = 0; j < 4; ++j) acc[m][j] = 0.f;

  for (int kh = 0; kh < 2; ++kh) {
    __syncthreads();  // protect previous half's reads
    for (int l = tid; l < 2048; l += 256) {
      int col = l >> 4, k4l = l & 15;
      Wl[l] = ((const float4*)W)[col * 32 + kh * 16 + k4l];
    }
    for (int l = tid; l < 512; l += 256) {
      int node = l >> 4, k4l = l & 15;
      float4 v = make_float4(0.f, 0.f, 0.f, 0.f);
      if (nb + node < n) v = ((const float4*)h)[(size_t)(nb + node) * 32 + kh * 16 + k4l];
      Hl[l] = v;
    }
    __syncthreads();
#pragma unroll
    for (int it = 0; it < 16; ++it) {
      const int k4 = (cg + it) & 15;
      float4 hv[4], wv[4];
#pragma unroll
      for (int m = 0; m < 4; ++m) hv[m] = Hl[(ng * 4 + m) * 16 + k4];
#pragma unroll
      for (int j = 0; j < 4; ++j) wv[j] = Wl[(cg * 4 + j) * 16 + k4];
#pragma unroll
      for (int m = 0; m < 4; ++m)
#pragma unroll
        for (int j = 0; j < 4; ++j)
          acc[m][j] += hv[m].x * wv[j].x + hv[m].y * wv[j].y +
                       hv[m].z * wv[j].z + hv[m].w * wv[j].w;
    }
  }
#pragma unroll
  for (int m = 0; m < 4; ++m) {
    int node = nb + ng * 4 + m;
    if (node < n) {
      float4 o = make_float4(acc[m][0], acc[m][1], acc[m][2], acc[m][3]);
      ((float4*)z)[(size_t)node * 32 + cg] = o;
    }
  }
}

// ---------------- K2: per-node attention scalars -------------------------------
// a_src[v] = z[v].w_fc[:128] + emb[v].w_emb[:128]
// a_dst[v] = z[v].w_fc[128:] + emb[v].w_emb[128:]
__global__ __launch_bounds__(256) void k_scal(const float* __restrict__ z,
                                              const float* __restrict__ emb,
                                              const float* __restrict__ w_fc,
                                              const float* __restrict__ w_emb,
                                              float* __restrict__ a_src,
                                              float* __restrict__ a_dst, int n) {
  const int lane = threadIdx.x & 63;
  const int v = blockIdx.x * 4 + (threadIdx.x >> 6);
  if (v >= n) return;
  float2 zz = ((const float2*)z)[(size_t)v * 64 + lane];
  float2 ee = ((const float2*)emb)[(size_t)v * 64 + lane];
  float2 wfs = ((const float2*)w_fc)[lane];
  float2 wfd = ((const float2*)w_fc)[64 + lane];
  float2 wes = ((const float2*)w_emb)[lane];
  float2 wed = ((const float2*)w_emb)[64 + lane];
  float ssrc = zz.x * wfs.x + zz.y * wfs.y + ee.x * wes.x + ee.y * wes.y;
  float sdst = zz.x * wfd.x + zz.y * wfd.y + ee.x * wed.x + ee.y * wed.y;
#pragma unroll
  for (int off = 32; off; off >>= 1) {
    ssrc += __shfl_xor(ssrc, off, 64);
    sdst += __shfl_xor(sdst, off, 64);
  }
  if (lane == 0) {
    a_src[v] = ssrc;
    a_dst[v] = sdst;
  }
}

// ---------------- K3: degree histogram ----------------------------------------
__global__ void k_hist(const int* __restrict__ dst, int* __restrict__ hist, int E) {
  int i = blockIdx.x * blockDim.x + threadIdx.x;
  const int stride = gridDim.x * blockDim.x;
  for (; i < E; i += stride) atomicAdd(&hist[dst[i]], 1);
}

// ---------------- K4: exclusive scan (single block, 8 elems/thread) -----------
__global__ __launch_bounds__(1024) void k_scan(const int* __restrict__ hist,
                                               int* __restrict__ row,
                                               int* __restrict__ cursor, int n) {
  __shared__ int sums[1024];
  __shared__ int s_carry;
  const int tid = threadIdx.x;
  if (tid == 0) s_carry = 0;
  __syncthreads();
  const int CH = 8192;
  for (int base = 0; base < n; base += CH) {
    const int idx0 = base + tid * 8;
    int v[8];
    int s = 0;
#pragma unroll
    for (int j = 0; j < 8; ++j) {
      int i = idx0 + j;
      v[j] = (i < n) ? hist[i] : 0;
      s += v[j];
    }
    sums[tid] = s;
    __syncthreads();
    for (int off = 1; off < 1024; off <<= 1) {
      int t = (tid >= off) ? sums[tid - off] : 0;
      __syncthreads();
      sums[tid] += t;
      __syncthreads();
    }
    int excl = s_carry + sums[tid] - s;
#pragma unroll
    for (int j = 0; j < 8; ++j) {
      int i = idx0 + j;
      if (i < n) {
        row[i] = excl;
        cursor[i] = excl;
      }
      excl += v[j];
    }
    __syncthreads();
    if (tid == 1023) s_carry += sums[1023];
    __syncthreads();
  }
  if (tid == 0) row[n] = s_carry;
}

// ---------------- K5: scatter edges into CSR buckets --------------------------
__global__ void k_scatter(const int* __restrict__ src, const int* __restrict__ dst,
                          int* __restrict__ cursor, int* __restrict__ csr_src,
                          int E) {
  int i = blockIdx.x * blockDim.x + threadIdx.x;
  const int stride = gridDim.x * blockDim.x;
  for (; i < E; i += stride) {
    int pos = atomicAdd(&cursor[dst[i]], 1);
    csr_src[pos] = src[i];
  }
}

// ---------------- K6: per-dst softmax + weighted aggregation ------------------
// One wave per dst node. Pass1: wave-max; Pass2: wave-sum of exp; Pass3: serial
// edge loop, lanes cover 128 dims as float2, coalesced 512B z-row reads.
__global__ __launch_bounds__(256) void k_agg(const float* __restrict__ z,
                                             const float* __restrict__ a_src,
                                             const float* __restrict__ a_dst,
                                             const int* __restrict__ row,
                                             const int* __restrict__ csr_src,
                                             float* __restrict__ out, int n) {
  const int lane = threadIdx.x & 63;
  const int v = blockIdx.x * 4 + (threadIdx.x >> 6);
  if (v >= n) return;
  const int beg = row[v], end = row[v + 1];
  const float adv = a_dst[v];

  float mx = -3.4e38f;
  for (int i = beg + lane; i < end; i += 64) {
    float a = a_src[csr_src[i]] + adv;
    float ev = a > 0.f ? a : 0.01f * a;
    mx = fmaxf(mx, ev);
  }
#pragma unroll
  for (int off = 32; off; off >>= 1) mx = fmaxf(mx, __shfl_xor(mx, off, 64));

  float sm = 0.f;
  for (int i = beg + lane; i < end; i += 64) {
    float a = a_src[csr_src[i]] + adv;
    float ev = a > 0.f ? a : 0.01f * a;
    sm += __expf(ev - mx);
  }
#pragma unroll
  for (int off = 32; off; off >>= 1) sm += __shfl_xor(sm, off, 64);

  const float inv = (end > beg) ? 1.f / sm : 0.f;
  float acc0 = 0.f, acc1 = 0.f;
  for (int i = beg; i < end; ++i) {
    int u = csr_src[i];  // uniform -> scalar load
    float a = a_src[u] + adv;
    float ev = a > 0.f ? a : 0.01f * a;
    float alpha = __expf(ev - mx) * inv;
    float2 zz = ((const float2*)z)[(size_t)u * 64 + lane];
    acc0 += alpha * zz.x;
    acc1 += alpha * zz.y;
  }
  ((float2*)out)[(size_t)v * 64 + lane] = make_float2(acc0, acc1);
}

extern "C" void kernel_launch(void* const* d_in, const int* in_sizes, int n_in,
                              void* d_out, int out_size, void* d_ws, size_t ws_size,
                              hipStream_t stream) {
  const float* h = (const float*)d_in[0];
  const float* emb = (const float*)d_in[1];
  const float* W = (const float*)d_in[2];
  const float* wfc = (const float*)d_in[3];
  const float* wemb = (const float*)d_in[4];
  const int* src = (const int*)d_in[5];
  const int* dst = (const int*)d_in[6];
  const int n = in_sizes[0] / D;
  const int E = in_sizes[5];

  char* ws = (char*)d_ws;
  size_t off = 0;
  auto alloc = [&](size_t bytes) {
    void* p = ws + off;
    off = (off + bytes + 255) & ~(size_t)255;
    return p;
  };
  float* z = (float*)alloc((size_t)n * D * 4);
  float* a_src = (float*)alloc((size_t)n * 4);
  float* a_dst = (float*)alloc((size_t)n * 4);
  int* hist = (int*)alloc((size_t)n * 4);
  int* row = (int*)alloc((size_t)(n + 1) * 4);
  int* cursor = (int*)alloc((size_t)n * 4);
  int* csr = (int*)alloc((size_t)E * 4);
  (void)off;
  (void)ws_size;

  hipMemsetAsync(hist, 0, (size_t)n * 4, stream);
  k_lin<<<(n + 31) / 32, 256, 0, stream>>>(h, W, z, n);
  k_scal<<<(n + 3) / 4, 256, 0, stream>>>(z, emb, wfc, wemb, a_src, a_dst, n);
  k_hist<<<2048, 256, 0, stream>>>(dst, hist, E);
  k_scan<<<1, 1024, 0, stream>>>(hist, row, cursor, n);
  k_scatter<<<2048, 256, 0, stream>>>(src, dst, cursor, csr, E);
  k_agg<<<(n + 3) / 4, 256, 0, stream>>>(z, a_src, a_dst, row, csr, (float*)d_out, n);
}

// Round 3
// 392.536 us; speedup vs baseline: 1.3321x; 1.3321x over previous
//
#include <hip/hip_runtime.h>
#include <hip/hip_bf16.h>

#define D 128

__device__ __forceinline__ unsigned short f2bf(float f) {
  unsigned u = __float_as_uint(f);
  unsigned r = (u + 0x7FFFu + ((u >> 16) & 1u)) >> 16;
  return (unsigned short)r;
}

// ---------------- K1: z = h @ W^T, fused s_fc dot, bf16 z output --------------
// 32 nodes/block, 256 threads, thread = 4 nodes x 4 cols. W in LDS (two 32KB
// halves). s_fc_src/dst[node] computed from fp32 accs via half-wave reduce.
__global__ __launch_bounds__(256) void k_lin(const float* __restrict__ h,
                                             const float* __restrict__ W,
                                             const float* __restrict__ w_fc,
                                             unsigned short* __restrict__ zb,
                                             float* __restrict__ sfc_s,
                                             float* __restrict__ sfc_d, int n) {
  __shared__ float4 Wl[128 * 16];  // [col][k4local]  32KB
  __shared__ float4 Hl[32 * 16];   // [node][k4local]  8KB
  const int tid = threadIdx.x;
  const int cg = tid & 31;   // col group: cols 4cg..4cg+3
  const int ng = tid >> 5;   // node group 0..7: nodes 4ng..4ng+3
  const int nb = blockIdx.x * 32;

  float acc[4][4];
#pragma unroll
  for (int m = 0; m < 4; ++m)
#pragma unroll
    for (int j = 0; j < 4; ++j) acc[m][j] = 0.f;

  for (int kh = 0; kh < 2; ++kh) {
    __syncthreads();
    for (int l = tid; l < 2048; l += 256) {
      int col = l >> 4, k4l = l & 15;
      Wl[l] = ((const float4*)W)[col * 32 + kh * 16 + k4l];
    }
    for (int l = tid; l < 512; l += 256) {
      int node = l >> 4, k4l = l & 15;
      float4 v = make_float4(0.f, 0.f, 0.f, 0.f);
      if (nb + node < n) v = ((const float4*)h)[(size_t)(nb + node) * 32 + kh * 16 + k4l];
      Hl[l] = v;
    }
    __syncthreads();
#pragma unroll
    for (int it = 0; it < 16; ++it) {
      const int k4 = (cg + it) & 15;
      float4 hv[4], wv[4];
#pragma unroll
      for (int m = 0; m < 4; ++m) hv[m] = Hl[(ng * 4 + m) * 16 + k4];
#pragma unroll
      for (int j = 0; j < 4; ++j) wv[j] = Wl[(cg * 4 + j) * 16 + k4];
#pragma unroll
      for (int m = 0; m < 4; ++m)
#pragma unroll
        for (int j = 0; j < 4; ++j)
          acc[m][j] += hv[m].x * wv[j].x + hv[m].y * wv[j].y +
                       hv[m].z * wv[j].z + hv[m].w * wv[j].w;
    }
  }

  const float4 wfs4 = ((const float4*)w_fc)[cg];        // w_fc[:128]
  const float4 wfd4 = ((const float4*)w_fc)[32 + cg];   // w_fc[128:]
#pragma unroll
  for (int m = 0; m < 4; ++m) {
    const int node = nb + ng * 4 + m;
    // bf16 z row
    if (node < n) {
      ushort4 o;
      o.x = f2bf(acc[m][0]); o.y = f2bf(acc[m][1]);
      o.z = f2bf(acc[m][2]); o.w = f2bf(acc[m][3]);
      ((ushort4*)zb)[(size_t)node * 32 + cg] = o;
    }
    // fused attention-fc scalars (from fp32 accumulators)
    float ps = acc[m][0] * wfs4.x + acc[m][1] * wfs4.y + acc[m][2] * wfs4.z + acc[m][3] * wfs4.w;
    float pd = acc[m][0] * wfd4.x + acc[m][1] * wfd4.y + acc[m][2] * wfd4.z + acc[m][3] * wfd4.w;
#pragma unroll
    for (int off = 16; off; off >>= 1) {
      ps += __shfl_xor(ps, off, 64);
      pd += __shfl_xor(pd, off, 64);
    }
    if (cg == 0 && node < n) {
      sfc_s[node] = ps;
      sfc_d[node] = pd;
    }
  }
}

// ---------------- K2: add embedding dot -> final a_src/a_dst ------------------
__global__ __launch_bounds__(256) void k_scal(const float* __restrict__ emb,
                                              const float* __restrict__ w_emb,
                                              const float* __restrict__ sfc_s,
                                              const float* __restrict__ sfc_d,
                                              float* __restrict__ a_src,
                                              float* __restrict__ a_dst, int n) {
  const int lane = threadIdx.x & 63;
  const int v = blockIdx.x * 4 + (threadIdx.x >> 6);
  if (v >= n) return;
  float2 ee = ((const float2*)emb)[(size_t)v * 64 + lane];
  float2 wes = ((const float2*)w_emb)[lane];
  float2 wed = ((const float2*)w_emb)[64 + lane];
  float ssrc = ee.x * wes.x + ee.y * wes.y;
  float sdst = ee.x * wed.x + ee.y * wed.y;
#pragma unroll
  for (int off = 32; off; off >>= 1) {
    ssrc += __shfl_xor(ssrc, off, 64);
    sdst += __shfl_xor(sdst, off, 64);
  }
  if (lane == 0) {
    a_src[v] = ssrc + sfc_s[v];
    a_dst[v] = sdst + sfc_d[v];
  }
}

// ---------------- K3: degree histogram ----------------------------------------
__global__ void k_hist(const int* __restrict__ dst, int* __restrict__ hist, int E) {
  int i = blockIdx.x * blockDim.x + threadIdx.x;
  const int stride = gridDim.x * blockDim.x;
  for (; i < E; i += stride) atomicAdd(&hist[dst[i]], 1);
}

// ---------------- K4a/b/c: parallel exclusive scan ----------------------------
__global__ __launch_bounds__(256) void k_part(const int* __restrict__ hist,
                                              int* __restrict__ partial, int n) {
  const int tid = threadIdx.x;
  int t = blockIdx.x * 256 + tid;
  int v = (t < n) ? hist[t] : 0;
#pragma unroll
  for (int off = 32; off; off >>= 1) v += __shfl_xor(v, off, 64);
  __shared__ int wsum[4];
  if ((tid & 63) == 0) wsum[tid >> 6] = v;
  __syncthreads();
  if (tid == 0) partial[blockIdx.x] = wsum[0] + wsum[1] + wsum[2] + wsum[3];
}

__global__ __launch_bounds__(256) void k_mid(const int* __restrict__ partial,
                                             int* __restrict__ chunk_off,
                                             int* __restrict__ row, int P, int n) {
  __shared__ int s[256];
  const int tid = threadIdx.x;
  int v = (tid < P) ? partial[tid] : 0;
  s[tid] = v;
  __syncthreads();
  for (int off = 1; off < 256; off <<= 1) {
    int a = (tid >= off) ? s[tid - off] : 0;
    __syncthreads();
    s[tid] += a;
    __syncthreads();
  }
  if (tid < P) chunk_off[tid] = s[tid] - v;
  if (tid == P - 1) row[n] = s[tid];
}

__global__ __launch_bounds__(256) void k_write(const int* __restrict__ hist,
                                               const int* __restrict__ chunk_off,
                                               int* __restrict__ row,
                                               int* __restrict__ cursor, int n) {
  __shared__ int s[256];
  const int tid = threadIdx.x;
  int t = blockIdx.x * 256 + tid;
  int v = (t < n) ? hist[t] : 0;
  s[tid] = v;
  __syncthreads();
  for (int off = 1; off < 256; off <<= 1) {
    int a = (tid >= off) ? s[tid - off] : 0;
    __syncthreads();
    s[tid] += a;
    __syncthreads();
  }
  int excl = chunk_off[blockIdx.x] + s[tid] - v;
  if (t < n) {
    row[t] = excl;
    cursor[t] = excl;
  }
}

// ---------------- K5: scatter edges + per-edge exp(leakyrelu) -----------------
__global__ void k_scatter(const int* __restrict__ src, const int* __restrict__ dst,
                          const float* __restrict__ a_src, const float* __restrict__ a_dst,
                          int* __restrict__ cursor, int2* __restrict__ csr2, int E) {
  int i = blockIdx.x * blockDim.x + threadIdx.x;
  const int stride = gridDim.x * blockDim.x;
  for (; i < E; i += stride) {
    int s = src[i], d = dst[i];
    float a = a_src[s] + a_dst[d];
    float e = a > 0.f ? a : 0.01f * a;
    float ew = __expf(e);
    int pos = atomicAdd(&cursor[d], 1);
    csr2[pos] = make_int2(s, __float_as_int(ew));
  }
}

// ---------------- K6: per-dst denom + weighted aggregation (bf16 z) -----------
// One wave per dst node. Pass1: coalesced sum of edge exps. Pass2: serial edge
// loop; 64 lanes cover 128 dims as 2 bf16 (one dword) -> 256B/row gather.
__global__ __launch_bounds__(256) void k_agg(const unsigned* __restrict__ zb,
                                             const int* __restrict__ row,
                                             const int2* __restrict__ csr2,
                                             float* __restrict__ out, int n) {
  const int lane = threadIdx.x & 63;
  const int v = blockIdx.x * 4 + (threadIdx.x >> 6);
  if (v >= n) return;
  const int beg = row[v], end = row[v + 1];

  float sm = 0.f;
  for (int i = beg + lane; i < end; i += 64) sm += __int_as_float(csr2[i].y);
#pragma unroll
  for (int off = 32; off; off >>= 1) sm += __shfl_xor(sm, off, 64);
  const float inv = (end > beg) ? 1.f / sm : 0.f;

  float acc0 = 0.f, acc1 = 0.f;
  for (int i = beg; i < end; ++i) {
    int2 e2 = csr2[i];                       // uniform -> scalar load
    float alpha = __int_as_float(e2.y) * inv;
    unsigned zz = zb[(size_t)e2.x * 64 + lane];
    acc0 += alpha * __uint_as_float(zz << 16);
    acc1 += alpha * __uint_as_float(zz & 0xffff0000u);
  }
  ((float2*)out)[(size_t)v * 64 + lane] = make_float2(acc0, acc1);
}

extern "C" void kernel_launch(void* const* d_in, const int* in_sizes, int n_in,
                              void* d_out, int out_size, void* d_ws, size_t ws_size,
                              hipStream_t stream) {
  const float* h = (const float*)d_in[0];
  const float* emb = (const float*)d_in[1];
  const float* W = (const float*)d_in[2];
  const float* wfc = (const float*)d_in[3];
  const float* wemb = (const float*)d_in[4];
  const int* src = (const int*)d_in[5];
  const int* dst = (const int*)d_in[6];
  const int n = in_sizes[0] / D;
  const int E = in_sizes[5];
  const int P = (n + 255) / 256;

  char* ws = (char*)d_ws;
  size_t off = 0;
  auto alloc = [&](size_t bytes) {
    void* p = ws + off;
    off = (off + bytes + 255) & ~(size_t)255;
    return p;
  };
  unsigned short* zb = (unsigned short*)alloc((size_t)n * D * 2);  // bf16 z
  float* sfc_s = (float*)alloc((size_t)n * 4);
  float* sfc_d = (float*)alloc((size_t)n * 4);
  float* a_src = (float*)alloc((size_t)n * 4);
  float* a_dst = (float*)alloc((size_t)n * 4);
  int* hist = (int*)alloc((size_t)n * 4);
  int* row = (int*)alloc((size_t)(n + 1) * 4);
  int* cursor = (int*)alloc((size_t)n * 4);
  int* partial = (int*)alloc((size_t)P * 4);
  int* chunk_off = (int*)alloc((size_t)P * 4);
  int2* csr2 = (int2*)alloc((size_t)E * 8);
  (void)off;
  (void)ws_size;

  (void)hipMemsetAsync(hist, 0, (size_t)n * 4, stream);
  k_lin<<<(n + 31) / 32, 256, 0, stream>>>(h, W, wfc, zb, sfc_s, sfc_d, n);
  k_scal<<<(n + 3) / 4, 256, 0, stream>>>(emb, wemb, sfc_s, sfc_d, a_src, a_dst, n);
  k_hist<<<2048, 256, 0, stream>>>(dst, hist, E);
  k_part<<<P, 256, 0, stream>>>(hist, partial, n);
  k_mid<<<1, 256, 0, stream>>>(partial, chunk_off, row, P, n);
  k_write<<<P, 256, 0, stream>>>(hist, chunk_off, row, cursor, n);
  k_scatter<<<2048, 256, 0, stream>>>(src, dst, a_src, a_dst, cursor, csr2, E);
  k_agg<<<(n + 3) / 4, 256, 0, stream>>>((const unsigned*)zb, row, csr2, (float*)d_out, n);
}

// Round 4
// 296.167 us; speedup vs baseline: 1.7655x; 1.3254x over previous
//
#include <hip/hip_runtime.h>
#include <hip/hip_bf16.h>

#define D 128

__device__ __forceinline__ unsigned short f2bf(float f) {
  unsigned u = __float_as_uint(f);
  unsigned r = (u + 0x7FFFu + ((u >> 16) & 1u)) >> 16;
  return (unsigned short)r;
}

// ---------------- K1: z = h @ W^T, fused s_fc dot, bf16 z output --------------
__global__ __launch_bounds__(256) void k_lin(const float* __restrict__ h,
                                             const float* __restrict__ W,
                                             const float* __restrict__ w_fc,
                                             unsigned short* __restrict__ zb,
                                             float* __restrict__ sfc_s,
                                             float* __restrict__ sfc_d, int n) {
  __shared__ float4 Wl[128 * 16];  // [col][k4local]  32KB
  __shared__ float4 Hl[32 * 16];   // [node][k4local]  8KB
  const int tid = threadIdx.x;
  const int cg = tid & 31;   // col group: cols 4cg..4cg+3
  const int ng = tid >> 5;   // node group 0..7: nodes 4ng..4ng+3
  const int nb = blockIdx.x * 32;

  float acc[4][4];
#pragma unroll
  for (int m = 0; m < 4; ++m)
#pragma unroll
    for (int j = 0; j < 4; ++j) acc[m][j] = 0.f;

  for (int kh = 0; kh < 2; ++kh) {
    __syncthreads();
    for (int l = tid; l < 2048; l += 256) {
      int col = l >> 4, k4l = l & 15;
      Wl[l] = ((const float4*)W)[col * 32 + kh * 16 + k4l];
    }
    for (int l = tid; l < 512; l += 256) {
      int node = l >> 4, k4l = l & 15;
      float4 v = make_float4(0.f, 0.f, 0.f, 0.f);
      if (nb + node < n) v = ((const float4*)h)[(size_t)(nb + node) * 32 + kh * 16 + k4l];
      Hl[l] = v;
    }
    __syncthreads();
#pragma unroll
    for (int it = 0; it < 16; ++it) {
      const int k4 = (cg + it) & 15;
      float4 hv[4], wv[4];
#pragma unroll
      for (int m = 0; m < 4; ++m) hv[m] = Hl[(ng * 4 + m) * 16 + k4];
#pragma unroll
      for (int j = 0; j < 4; ++j) wv[j] = Wl[(cg * 4 + j) * 16 + k4];
#pragma unroll
      for (int m = 0; m < 4; ++m)
#pragma unroll
        for (int j = 0; j < 4; ++j)
          acc[m][j] += hv[m].x * wv[j].x + hv[m].y * wv[j].y +
                       hv[m].z * wv[j].z + hv[m].w * wv[j].w;
    }
  }

  const float4 wfs4 = ((const float4*)w_fc)[cg];
  const float4 wfd4 = ((const float4*)w_fc)[32 + cg];
#pragma unroll
  for (int m = 0; m < 4; ++m) {
    const int node = nb + ng * 4 + m;
    if (node < n) {
      ushort4 o;
      o.x = f2bf(acc[m][0]); o.y = f2bf(acc[m][1]);
      o.z = f2bf(acc[m][2]); o.w = f2bf(acc[m][3]);
      ((ushort4*)zb)[(size_t)node * 32 + cg] = o;
    }
    float ps = acc[m][0] * wfs4.x + acc[m][1] * wfs4.y + acc[m][2] * wfs4.z + acc[m][3] * wfs4.w;
    float pd = acc[m][0] * wfd4.x + acc[m][1] * wfd4.y + acc[m][2] * wfd4.z + acc[m][3] * wfd4.w;
#pragma unroll
    for (int off = 16; off; off >>= 1) {
      ps += __shfl_xor(ps, off, 64);
      pd += __shfl_xor(pd, off, 64);
    }
    if (cg == 0 && node < n) {
      sfc_s[node] = ps;
      sfc_d[node] = pd;
    }
  }
}

// ---------------- K2: add embedding dot -> final a_src/a_dst ------------------
__global__ __launch_bounds__(256) void k_scal(const float* __restrict__ emb,
                                              const float* __restrict__ w_emb,
                                              const float* __restrict__ sfc_s,
                                              const float* __restrict__ sfc_d,
                                              float* __restrict__ a_src,
                                              float* __restrict__ a_dst, int n) {
  const int lane = threadIdx.x & 63;
  const int v = blockIdx.x * 4 + (threadIdx.x >> 6);
  if (v >= n) return;
  float2 ee = ((const float2*)emb)[(size_t)v * 64 + lane];
  float2 wes = ((const float2*)w_emb)[lane];
  float2 wed = ((const float2*)w_emb)[64 + lane];
  float ssrc = ee.x * wes.x + ee.y * wes.y;
  float sdst = ee.x * wed.x + ee.y * wed.y;
#pragma unroll
  for (int off = 32; off; off >>= 1) {
    ssrc += __shfl_xor(ssrc, off, 64);
    sdst += __shfl_xor(sdst, off, 64);
  }
  if (lane == 0) {
    a_src[v] = ssrc + sfc_s[v];
    a_dst[v] = sdst + sfc_d[v];
  }
}

// ---------------- K3: degree histogram ----------------------------------------
__global__ void k_hist(const int* __restrict__ dst, int* __restrict__ hist, int E) {
  int i = blockIdx.x * blockDim.x + threadIdx.x;
  const int stride = gridDim.x * blockDim.x;
  for (; i < E; i += stride) atomicAdd(&hist[dst[i]], 1);
}

// ---------------- K4a/b/c: parallel exclusive scan ----------------------------
__global__ __launch_bounds__(256) void k_part(const int* __restrict__ hist,
                                              int* __restrict__ partial, int n) {
  const int tid = threadIdx.x;
  int t = blockIdx.x * 256 + tid;
  int v = (t < n) ? hist[t] : 0;
#pragma unroll
  for (int off = 32; off; off >>= 1) v += __shfl_xor(v, off, 64);
  __shared__ int wsum[4];
  if ((tid & 63) == 0) wsum[tid >> 6] = v;
  __syncthreads();
  if (tid == 0) partial[blockIdx.x] = wsum[0] + wsum[1] + wsum[2] + wsum[3];
}

__global__ __launch_bounds__(256) void k_mid(const int* __restrict__ partial,
                                             int* __restrict__ chunk_off,
                                             int* __restrict__ row, int P, int n) {
  __shared__ int s[256];
  const int tid = threadIdx.x;
  int v = (tid < P) ? partial[tid] : 0;
  s[tid] = v;
  __syncthreads();
  for (int off = 1; off < 256; off <<= 1) {
    int a = (tid >= off) ? s[tid - off] : 0;
    __syncthreads();
    s[tid] += a;
    __syncthreads();
  }
  if (tid < P) chunk_off[tid] = s[tid] - v;
  if (tid == P - 1) row[n] = s[tid];
}

__global__ __launch_bounds__(256) void k_write(const int* __restrict__ hist,
                                               const int* __restrict__ chunk_off,
                                               int* __restrict__ row,
                                               int* __restrict__ cursor, int n) {
  __shared__ int s[256];
  const int tid = threadIdx.x;
  int t = blockIdx.x * 256 + tid;
  int v = (t < n) ? hist[t] : 0;
  s[tid] = v;
  __syncthreads();
  for (int off = 1; off < 256; off <<= 1) {
    int a = (tid >= off) ? s[tid - off] : 0;
    __syncthreads();
    s[tid] += a;
    __syncthreads();
  }
  int excl = chunk_off[blockIdx.x] + s[tid] - v;
  if (t < n) {
    row[t] = excl;
    cursor[t] = excl;
  }
}

// ---------------- K5: scatter edges + per-edge exp(leakyrelu) -----------------
__global__ void k_scatter(const int* __restrict__ src, const int* __restrict__ dst,
                          const float* __restrict__ a_src, const float* __restrict__ a_dst,
                          int* __restrict__ cursor, int2* __restrict__ csr2, int E) {
  int i = blockIdx.x * blockDim.x + threadIdx.x;
  const int stride = gridDim.x * blockDim.x;
  for (; i < E; i += stride) {
    int s = src[i], d = dst[i];
    float a = a_src[s] + a_dst[d];
    float e = a > 0.f ? a : 0.01f * a;
    float ew = __expf(e);
    int pos = atomicAdd(&cursor[d], 1);
    csr2[pos] = make_int2(s, __float_as_int(ew));
  }
}

// ---------------- K6: single-pass weighted aggregation (bf16 z) ---------------
// One wave per dst node, split into 4x16-lane groups; group g handles edges
// beg+g, beg+g+4, ... Each group reads a full 256B z row (uint4/lane).
// Accumulate unnormalized sum + denom, cross-group shfl reduce, divide, write.
__global__ __launch_bounds__(256) void k_agg(const unsigned short* __restrict__ zb,
                                             const int* __restrict__ row,
                                             const int2* __restrict__ csr2,
                                             float* __restrict__ out, int n) {
  const int lane = threadIdx.x & 63;
  const int grp = lane >> 4;   // 0..3: edge subset
  const int sub = lane & 15;   // 16B chunk within row -> dims 8*sub..8*sub+7
  const int v = blockIdx.x * 4 + (threadIdx.x >> 6);
  if (v >= n) return;
  const int beg = row[v], end = row[v + 1];

  float accf[8];
#pragma unroll
  for (int j = 0; j < 8; ++j) accf[j] = 0.f;
  float ews = 0.f;

#pragma unroll 2
  for (int i = beg + grp; i < end; i += 4) {
    const int2 e2 = csr2[i];
    const float ew = __int_as_float(e2.y);
    const uint4 zz = ((const uint4*)zb)[(size_t)e2.x * 16 + sub];
    ews += ew;
    accf[0] += ew * __uint_as_float(zz.x << 16);
    accf[1] += ew * __uint_as_float(zz.x & 0xffff0000u);
    accf[2] += ew * __uint_as_float(zz.y << 16);
    accf[3] += ew * __uint_as_float(zz.y & 0xffff0000u);
    accf[4] += ew * __uint_as_float(zz.z << 16);
    accf[5] += ew * __uint_as_float(zz.z & 0xffff0000u);
    accf[6] += ew * __uint_as_float(zz.w << 16);
    accf[7] += ew * __uint_as_float(zz.w & 0xffff0000u);
  }

  // reduce across the 4 groups (lanes l, l+16, l+32, l+48 share dims)
#pragma unroll
  for (int off = 16; off <= 32; off <<= 1) {
    ews += __shfl_xor(ews, off, 64);
#pragma unroll
    for (int j = 0; j < 8; ++j) accf[j] += __shfl_xor(accf[j], off, 64);
  }

  if (grp == 0) {
    const float inv = (end > beg) ? 1.f / ews : 0.f;
    float4 o0 = make_float4(accf[0] * inv, accf[1] * inv, accf[2] * inv, accf[3] * inv);
    float4 o1 = make_float4(accf[4] * inv, accf[5] * inv, accf[6] * inv, accf[7] * inv);
    ((float4*)out)[(size_t)v * 32 + sub * 2] = o0;
    ((float4*)out)[(size_t)v * 32 + sub * 2 + 1] = o1;
  }
}

extern "C" void kernel_launch(void* const* d_in, const int* in_sizes, int n_in,
                              void* d_out, int out_size, void* d_ws, size_t ws_size,
                              hipStream_t stream) {
  const float* h = (const float*)d_in[0];
  const float* emb = (const float*)d_in[1];
  const float* W = (const float*)d_in[2];
  const float* wfc = (const float*)d_in[3];
  const float* wemb = (const float*)d_in[4];
  const int* src = (const int*)d_in[5];
  const int* dst = (const int*)d_in[6];
  const int n = in_sizes[0] / D;
  const int E = in_sizes[5];
  const int P = (n + 255) / 256;

  char* ws = (char*)d_ws;
  size_t off = 0;
  auto alloc = [&](size_t bytes) {
    void* p = ws + off;
    off = (off + bytes + 255) & ~(size_t)255;
    return p;
  };
  unsigned short* zb = (unsigned short*)alloc((size_t)n * D * 2);  // bf16 z
  float* sfc_s = (float*)alloc((size_t)n * 4);
  float* sfc_d = (float*)alloc((size_t)n * 4);
  float* a_src = (float*)alloc((size_t)n * 4);
  float* a_dst = (float*)alloc((size_t)n * 4);
  int* hist = (int*)alloc((size_t)n * 4);
  int* row = (int*)alloc((size_t)(n + 1) * 4);
  int* cursor = (int*)alloc((size_t)n * 4);
  int* partial = (int*)alloc((size_t)P * 4);
  int* chunk_off = (int*)alloc((size_t)P * 4);
  int2* csr2 = (int2*)alloc((size_t)E * 8);
  (void)off;
  (void)ws_size;

  (void)hipMemsetAsync(hist, 0, (size_t)n * 4, stream);
  k_lin<<<(n + 31) / 32, 256, 0, stream>>>(h, W, wfc, zb, sfc_s, sfc_d, n);
  k_scal<<<(n + 3) / 4, 256, 0, stream>>>(emb, wemb, sfc_s, sfc_d, a_src, a_dst, n);
  k_hist<<<2048, 256, 0, stream>>>(dst, hist, E);
  k_part<<<P, 256, 0, stream>>>(hist, partial, n);
  k_mid<<<1, 256, 0, stream>>>(partial, chunk_off, row, P, n);
  k_write<<<P, 256, 0, stream>>>(hist, chunk_off, row, cursor, n);
  k_scatter<<<2048, 256, 0, stream>>>(src, dst, a_src, a_dst, cursor, csr2, E);
  k_agg<<<(n + 3) / 4, 256, 0, stream>>>(zb, row, csr2, (float*)d_out, n);
}

// Round 5
// 287.309 us; speedup vs baseline: 1.8199x; 1.0308x over previous
//
#include <hip/hip_runtime.h>
#include <hip/hip_bf16.h>

#define D 128

typedef __attribute__((ext_vector_type(8))) short short8;
typedef __attribute__((ext_vector_type(4))) float f32x4;

__device__ __forceinline__ unsigned short f2bf(float f) {
  unsigned u = __float_as_uint(f);
  unsigned r = (u + 0x7FFFu + ((u >> 16) & 1u)) >> 16;
  return (unsigned short)r;
}

// ---------------- K0: W fp32 -> bf16 ------------------------------------------
__global__ __launch_bounds__(256) void k_wconv(const float* __restrict__ W,
                                               unsigned short* __restrict__ Wb) {
  const int i = blockIdx.x * 256 + threadIdx.x;  // float4 index
  float4 f = ((const float4*)W)[i];
  ushort4 o;
  o.x = f2bf(f.x); o.y = f2bf(f.y); o.z = f2bf(f.z); o.w = f2bf(f.w);
  ((ushort4*)Wb)[i] = o;
}

// ---------------- K1: z = h @ W^T via MFMA, fused s_fc, paired-dword z --------
// 4 waves/block, wave = 16 nodes. A = h rows (fp32->bf16 in reg), B = Wb.
// z stored as dwords: zd[row*64 + d] = bf16pair(col d, col d+64).
// A frag: row = lane&15, k = 8*(lane>>4)+j ; B frag: col = lane&15, same k.
// D frag: col = lane&15, row = (lane>>4)*4 + r   [m89-verified]
__global__ __launch_bounds__(256) void k_lin(const float* __restrict__ h,
                                             const unsigned short* __restrict__ Wb,
                                             const float* __restrict__ w_fc,
                                             unsigned* __restrict__ zd,
                                             float* __restrict__ sfc_s,
                                             float* __restrict__ sfc_d, int n) {
  const int lane = threadIdx.x & 63;
  const int wid = threadIdx.x >> 6;
  const int m0 = blockIdx.x * 64 + wid * 16;
  if (m0 >= n) return;
  const int c = lane & 15;  // A-row / B-col / D-col within tile
  const int g = lane >> 4;  // k-group

  int arow = m0 + c;
  if (arow >= n) arow = n - 1;
  const float4* hrow = (const float4*)(h + (size_t)arow * 128);

  short8 afr[4];
#pragma unroll
  for (int s = 0; s < 4; ++s) {
    float4 f0 = hrow[8 * s + 2 * g];
    float4 f1 = hrow[8 * s + 2 * g + 1];
    short8 a;
    a[0] = (short)f2bf(f0.x); a[1] = (short)f2bf(f0.y);
    a[2] = (short)f2bf(f0.z); a[3] = (short)f2bf(f0.w);
    a[4] = (short)f2bf(f1.x); a[5] = (short)f2bf(f1.y);
    a[6] = (short)f2bf(f1.z); a[7] = (short)f2bf(f1.w);
    afr[s] = a;
  }

  f32x4 acc[8];
#pragma unroll
  for (int t = 0; t < 8; ++t) acc[t] = (f32x4){0.f, 0.f, 0.f, 0.f};

#pragma unroll
  for (int s = 0; s < 4; ++s) {
#pragma unroll
    for (int t = 0; t < 8; ++t) {
      short8 b = *(const short8*)(Wb + ((size_t)(t * 16 + c) * 128 + 32 * s + 8 * g));
      acc[t] = __builtin_amdgcn_mfma_f32_16x16x32_bf16(afr[s], b, acc[t], 0, 0, 0);
    }
  }

  float wfs[8], wfd[8];
#pragma unroll
  for (int t = 0; t < 8; ++t) {
    wfs[t] = w_fc[t * 16 + c];
    wfd[t] = w_fc[128 + t * 16 + c];
  }

  const int rbase = m0 + 4 * g;
#pragma unroll
  for (int r = 0; r < 4; ++r) {
    const int row = rbase + r;
    if (row < n) {
#pragma unroll
      for (int tp = 0; tp < 4; ++tp) {
        unsigned dw = ((unsigned)f2bf(acc[tp + 4][r]) << 16) | (unsigned)f2bf(acc[tp][r]);
        zd[(size_t)row * 64 + tp * 16 + c] = dw;
      }
    }
    float ps = 0.f, pd = 0.f;
#pragma unroll
    for (int t = 0; t < 8; ++t) {
      ps += acc[t][r] * wfs[t];
      pd += acc[t][r] * wfd[t];
    }
#pragma unroll
    for (int off = 1; off < 16; off <<= 1) {
      ps += __shfl_xor(ps, off, 64);
      pd += __shfl_xor(pd, off, 64);
    }
    if (c == 0 && row < n) {
      sfc_s[row] = ps;
      sfc_d[row] = pd;
    }
  }
}

// ---------------- K2: add embedding dot -> final a_src/a_dst ------------------
__global__ __launch_bounds__(256) void k_scal(const float* __restrict__ emb,
                                              const float* __restrict__ w_emb,
                                              const float* __restrict__ sfc_s,
                                              const float* __restrict__ sfc_d,
                                              float* __restrict__ a_src,
                                              float* __restrict__ a_dst, int n) {
  const int lane = threadIdx.x & 63;
  const int v = blockIdx.x * 4 + (threadIdx.x >> 6);
  if (v >= n) return;
  float2 ee = ((const float2*)emb)[(size_t)v * 64 + lane];
  float2 wes = ((const float2*)w_emb)[lane];
  float2 wed = ((const float2*)w_emb)[64 + lane];
  float ssrc = ee.x * wes.x + ee.y * wes.y;
  float sdst = ee.x * wed.x + ee.y * wed.y;
#pragma unroll
  for (int off = 32; off; off >>= 1) {
    ssrc += __shfl_xor(ssrc, off, 64);
    sdst += __shfl_xor(sdst, off, 64);
  }
  if (lane == 0) {
    a_src[v] = ssrc + sfc_s[v];
    a_dst[v] = sdst + sfc_d[v];
  }
}

// ---------------- K3: degree histogram ----------------------------------------
__global__ void k_hist(const int* __restrict__ dst, int* __restrict__ hist, int E) {
  int i = blockIdx.x * blockDim.x + threadIdx.x;
  const int stride = gridDim.x * blockDim.x;
  for (; i < E; i += stride) atomicAdd(&hist[dst[i]], 1);
}

// ---------------- K4a/b/c: parallel exclusive scan ----------------------------
__global__ __launch_bounds__(256) void k_part(const int* __restrict__ hist,
                                              int* __restrict__ partial, int n) {
  const int tid = threadIdx.x;
  int t = blockIdx.x * 256 + tid;
  int v = (t < n) ? hist[t] : 0;
#pragma unroll
  for (int off = 32; off; off >>= 1) v += __shfl_xor(v, off, 64);
  __shared__ int wsum[4];
  if ((tid & 63) == 0) wsum[tid >> 6] = v;
  __syncthreads();
  if (tid == 0) partial[blockIdx.x] = wsum[0] + wsum[1] + wsum[2] + wsum[3];
}

__global__ __launch_bounds__(256) void k_mid(const int* __restrict__ partial,
                                             int* __restrict__ chunk_off,
                                             int* __restrict__ row, int P, int n) {
  __shared__ int s[256];
  const int tid = threadIdx.x;
  int v = (tid < P) ? partial[tid] : 0;
  s[tid] = v;
  __syncthreads();
  for (int off = 1; off < 256; off <<= 1) {
    int a = (tid >= off) ? s[tid - off] : 0;
    __syncthreads();
    s[tid] += a;
    __syncthreads();
  }
  if (tid < P) chunk_off[tid] = s[tid] - v;
  if (tid == P - 1) row[n] = s[tid];
}

__global__ __launch_bounds__(256) void k_write(const int* __restrict__ hist,
                                               const int* __restrict__ chunk_off,
                                               int* __restrict__ row,
                                               int* __restrict__ cursor, int n) {
  __shared__ int s[256];
  const int tid = threadIdx.x;
  int t = blockIdx.x * 256 + tid;
  int v = (t < n) ? hist[t] : 0;
  s[tid] = v;
  __syncthreads();
  for (int off = 1; off < 256; off <<= 1) {
    int a = (tid >= off) ? s[tid - off] : 0;
    __syncthreads();
    s[tid] += a;
    __syncthreads();
  }
  int excl = chunk_off[blockIdx.x] + s[tid] - v;
  if (t < n) {
    row[t] = excl;
    cursor[t] = excl;
  }
}

// ---------------- K5: scatter edge src ids into CSR buckets (4B records) ------
__global__ void k_scatter(const int* __restrict__ src, const int* __restrict__ dst,
                          int* __restrict__ cursor, int* __restrict__ csr, int E) {
  int i = blockIdx.x * blockDim.x + threadIdx.x;
  const int stride = gridDim.x * blockDim.x;
  for (; i < E; i += stride) {
    int pos = atomicAdd(&cursor[dst[i]], 1);
    csr[pos] = src[i];
  }
}

// ---------------- K6: single-pass weighted aggregation (paired-dword z) -------
// Wave = dst node, 4x16-lane groups over edges; recompute ew from a_src/a_dst.
// zd dword d = cols (d, d+64). Output: lane sub writes cols 4sub..+3, 64+4sub..+3.
__global__ __launch_bounds__(256) void k_agg(const unsigned* __restrict__ zd,
                                             const float* __restrict__ a_src,
                                             const float* __restrict__ a_dst,
                                             const int* __restrict__ row,
                                             const int* __restrict__ csr,
                                             float* __restrict__ out, int n) {
  const int lane = threadIdx.x & 63;
  const int grp = lane >> 4;
  const int sub = lane & 15;
  const int v = blockIdx.x * 4 + (threadIdx.x >> 6);
  if (v >= n) return;
  const int beg = row[v], end = row[v + 1];
  const float adv = a_dst[v];

  float accf[8];
#pragma unroll
  for (int j = 0; j < 8; ++j) accf[j] = 0.f;
  float ews = 0.f;

#pragma unroll 2
  for (int i = beg + grp; i < end; i += 4) {
    const int u = csr[i];
    const float a = a_src[u] + adv;
    const float e = a > 0.f ? a : 0.01f * a;
    const float ew = __expf(e);
    const uint4 zz = ((const uint4*)zd)[(size_t)u * 16 + sub];
    ews += ew;
    accf[0] += ew * __uint_as_float(zz.x << 16);
    accf[1] += ew * __uint_as_float(zz.x & 0xffff0000u);
    accf[2] += ew * __uint_as_float(zz.y << 16);
    accf[3] += ew * __uint_as_float(zz.y & 0xffff0000u);
    accf[4] += ew * __uint_as_float(zz.z << 16);
    accf[5] += ew * __uint_as_float(zz.z & 0xffff0000u);
    accf[6] += ew * __uint_as_float(zz.w << 16);
    accf[7] += ew * __uint_as_float(zz.w & 0xffff0000u);
  }

#pragma unroll
  for (int off = 16; off <= 32; off <<= 1) {
    ews += __shfl_xor(ews, off, 64);
#pragma unroll
    for (int j = 0; j < 8; ++j) accf[j] += __shfl_xor(accf[j], off, 64);
  }

  if (grp == 0) {
    const float inv = (end > beg) ? 1.f / ews : 0.f;
    // dword q of uint4 -> cols (4sub+q, 4sub+q+64); accf[2q]=lo, accf[2q+1]=hi
    float4 olo = make_float4(accf[0] * inv, accf[2] * inv, accf[4] * inv, accf[6] * inv);
    float4 ohi = make_float4(accf[1] * inv, accf[3] * inv, accf[5] * inv, accf[7] * inv);
    ((float4*)out)[(size_t)v * 32 + sub] = olo;        // cols 4sub..4sub+3
    ((float4*)out)[(size_t)v * 32 + 16 + sub] = ohi;   // cols 64+4sub..64+4sub+3
  }
}

extern "C" void kernel_launch(void* const* d_in, const int* in_sizes, int n_in,
                              void* d_out, int out_size, void* d_ws, size_t ws_size,
                              hipStream_t stream) {
  const float* h = (const float*)d_in[0];
  const float* emb = (const float*)d_in[1];
  const float* W = (const float*)d_in[2];
  const float* wfc = (const float*)d_in[3];
  const float* wemb = (const float*)d_in[4];
  const int* src = (const int*)d_in[5];
  const int* dst = (const int*)d_in[6];
  const int n = in_sizes[0] / D;
  const int E = in_sizes[5];
  const int P = (n + 255) / 256;

  char* ws = (char*)d_ws;
  size_t off = 0;
  auto alloc = [&](size_t bytes) {
    void* p = ws + off;
    off = (off + bytes + 255) & ~(size_t)255;
    return p;
  };
  unsigned* zd = (unsigned*)alloc((size_t)n * 64 * 4);     // paired-dword bf16 z
  unsigned short* Wb = (unsigned short*)alloc(D * D * 2);  // bf16 W
  float* sfc_s = (float*)alloc((size_t)n * 4);
  float* sfc_d = (float*)alloc((size_t)n * 4);
  float* a_src = (float*)alloc((size_t)n * 4);
  float* a_dst = (float*)alloc((size_t)n * 4);
  int* hist = (int*)alloc((size_t)n * 4);
  int* row = (int*)alloc((size_t)(n + 1) * 4);
  int* cursor = (int*)alloc((size_t)n * 4);
  int* partial = (int*)alloc((size_t)P * 4);
  int* chunk_off = (int*)alloc((size_t)P * 4);
  int* csr = (int*)alloc((size_t)E * 4);
  (void)off;
  (void)ws_size;

  (void)hipMemsetAsync(hist, 0, (size_t)n * 4, stream);
  k_wconv<<<(D * D / 4 + 255) / 256, 256, 0, stream>>>(W, Wb);
  k_lin<<<(n + 63) / 64, 256, 0, stream>>>(h, Wb, wfc, zd, sfc_s, sfc_d, n);
  k_scal<<<(n + 3) / 4, 256, 0, stream>>>(emb, wemb, sfc_s, sfc_d, a_src, a_dst, n);
  k_hist<<<2048, 256, 0, stream>>>(dst, hist, E);
  k_part<<<P, 256, 0, stream>>>(hist, partial, n);
  k_mid<<<1, 256, 0, stream>>>(partial, chunk_off, row, P, n);
  k_write<<<P, 256, 0, stream>>>(hist, chunk_off, row, cursor, n);
  k_scatter<<<2048, 256, 0, stream>>>(src, dst, cursor, csr, E);
  k_agg<<<(n + 3) / 4, 256, 0, stream>>>(zd, a_src, a_dst, row, csr, (float*)d_out, n);
}

// Round 6
// 141.941 us; speedup vs baseline: 3.6838x; 2.0241x over previous
//
#include <hip/hip_runtime.h>
#include <hip/hip_bf16.h>

#define D 128
#define BSH 7            // 128 dsts per bin
#define BDST 128
#define NCH 256          // edge chunks
#define CAP 6144         // staged records per bin (mean 4096, +32 sigma)

typedef __attribute__((ext_vector_type(8))) short short8;
typedef __attribute__((ext_vector_type(4))) float f32x4;

__device__ __forceinline__ unsigned short f2bf(float f) {
  unsigned u = __float_as_uint(f);
  unsigned r = (u + 0x7FFFu + ((u >> 16) & 1u)) >> 16;
  return (unsigned short)r;
}

// ---------------- K0: W fp32 -> bf16 ------------------------------------------
__global__ __launch_bounds__(256) void k_wconv(const float* __restrict__ W,
                                               unsigned short* __restrict__ Wb) {
  const int i = blockIdx.x * 256 + threadIdx.x;
  float4 f = ((const float4*)W)[i];
  ushort4 o;
  o.x = f2bf(f.x); o.y = f2bf(f.y); o.z = f2bf(f.z); o.w = f2bf(f.w);
  ((ushort4*)Wb)[i] = o;
}

// ---------------- K1: z = h @ W^T via MFMA, fused s_fc, paired-dword z --------
__global__ __launch_bounds__(256) void k_lin(const float* __restrict__ h,
                                             const unsigned short* __restrict__ Wb,
                                             const float* __restrict__ w_fc,
                                             unsigned* __restrict__ zd,
                                             float* __restrict__ sfc_s,
                                             float* __restrict__ sfc_d, int n) {
  const int lane = threadIdx.x & 63;
  const int wid = threadIdx.x >> 6;
  const int m0 = blockIdx.x * 64 + wid * 16;
  if (m0 >= n) return;
  const int c = lane & 15;
  const int g = lane >> 4;

  int arow = m0 + c;
  if (arow >= n) arow = n - 1;
  const float4* hrow = (const float4*)(h + (size_t)arow * 128);

  short8 afr[4];
#pragma unroll
  for (int s = 0; s < 4; ++s) {
    float4 f0 = hrow[8 * s + 2 * g];
    float4 f1 = hrow[8 * s + 2 * g + 1];
    short8 a;
    a[0] = (short)f2bf(f0.x); a[1] = (short)f2bf(f0.y);
    a[2] = (short)f2bf(f0.z); a[3] = (short)f2bf(f0.w);
    a[4] = (short)f2bf(f1.x); a[5] = (short)f2bf(f1.y);
    a[6] = (short)f2bf(f1.z); a[7] = (short)f2bf(f1.w);
    afr[s] = a;
  }

  f32x4 acc[8];
#pragma unroll
  for (int t = 0; t < 8; ++t) acc[t] = (f32x4){0.f, 0.f, 0.f, 0.f};

#pragma unroll
  for (int s = 0; s < 4; ++s) {
#pragma unroll
    for (int t = 0; t < 8; ++t) {
      short8 b = *(const short8*)(Wb + ((size_t)(t * 16 + c) * 128 + 32 * s + 8 * g));
      acc[t] = __builtin_amdgcn_mfma_f32_16x16x32_bf16(afr[s], b, acc[t], 0, 0, 0);
    }
  }

  float wfs[8], wfd[8];
#pragma unroll
  for (int t = 0; t < 8; ++t) {
    wfs[t] = w_fc[t * 16 + c];
    wfd[t] = w_fc[128 + t * 16 + c];
  }

  const int rbase = m0 + 4 * g;
#pragma unroll
  for (int r = 0; r < 4; ++r) {
    const int row = rbase + r;
    if (row < n) {
#pragma unroll
      for (int tp = 0; tp < 4; ++tp) {
        unsigned dw = ((unsigned)f2bf(acc[tp + 4][r]) << 16) | (unsigned)f2bf(acc[tp][r]);
        zd[(size_t)row * 64 + tp * 16 + c] = dw;
      }
    }
    float ps = 0.f, pd = 0.f;
#pragma unroll
    for (int t = 0; t < 8; ++t) {
      ps += acc[t][r] * wfs[t];
      pd += acc[t][r] * wfd[t];
    }
#pragma unroll
    for (int off = 1; off < 16; off <<= 1) {
      ps += __shfl_xor(ps, off, 64);
      pd += __shfl_xor(pd, off, 64);
    }
    if (c == 0 && row < n) {
      sfc_s[row] = ps;
      sfc_d[row] = pd;
    }
  }
}

// ---------------- K2: add embedding dot -> final a_src/a_dst ------------------
__global__ __launch_bounds__(256) void k_scal(const float* __restrict__ emb,
                                              const float* __restrict__ w_emb,
                                              const float* __restrict__ sfc_s,
                                              const float* __restrict__ sfc_d,
                                              float* __restrict__ a_src,
                                              float* __restrict__ a_dst, int n) {
  const int lane = threadIdx.x & 63;
  const int v = blockIdx.x * 4 + (threadIdx.x >> 6);
  if (v >= n) return;
  float2 ee = ((const float2*)emb)[(size_t)v * 64 + lane];
  float2 wes = ((const float2*)w_emb)[lane];
  float2 wed = ((const float2*)w_emb)[64 + lane];
  float ssrc = ee.x * wes.x + ee.y * wes.y;
  float sdst = ee.x * wed.x + ee.y * wed.y;
#pragma unroll
  for (int off = 32; off; off >>= 1) {
    ssrc += __shfl_xor(ssrc, off, 64);
    sdst += __shfl_xor(sdst, off, 64);
  }
  if (lane == 0) {
    a_src[v] = ssrc + sfc_s[v];
    a_dst[v] = sdst + sfc_d[v];
  }
}

// ---------------- CSR build pass 1: per-chunk bin histogram -------------------
__global__ __launch_bounds__(256) void k_chist(const int* __restrict__ dst,
                                               int* __restrict__ cnt,
                                               int E, int NB, int CHSZ) {
  __shared__ int hl[512];
  const int tid = threadIdx.x, c = blockIdx.x;
  for (int i = tid; i < NB; i += 256) hl[i] = 0;
  __syncthreads();
  const int beg = c * CHSZ, end = min(beg + CHSZ, E);
  for (int i = beg + tid; i < end; i += 256) atomicAdd(&hl[dst[i] >> BSH], 1);
  __syncthreads();
  for (int b = tid; b < NB; b += 256) cnt[(size_t)b * NCH + c] = hl[b];
}

// ---------------- scan: ks1 (tile sums), ks2 (scan partials), ks3 (apply) -----
__global__ __launch_bounds__(256) void ks1(const int* __restrict__ cnt,
                                           int* __restrict__ partial, int M) {
  const int tid = threadIdx.x;
  const int t0 = blockIdx.x * 1024 + tid * 4;
  int s = 0;
  if (t0 + 3 < M) {
    int4 v = *(const int4*)(cnt + t0);
    s = v.x + v.y + v.z + v.w;
  } else {
    for (int j = 0; j < 4; ++j)
      if (t0 + j < M) s += cnt[t0 + j];
  }
#pragma unroll
  for (int off = 32; off; off >>= 1) s += __shfl_xor(s, off, 64);
  __shared__ int w[4];
  if ((tid & 63) == 0) w[tid >> 6] = s;
  __syncthreads();
  if (tid == 0) partial[blockIdx.x] = w[0] + w[1] + w[2] + w[3];
}

__global__ __launch_bounds__(256) void ks2(const int* __restrict__ partial,
                                           int* __restrict__ chunk_off, int P) {
  __shared__ int s[256];
  const int tid = threadIdx.x;
  int v = (tid < P) ? partial[tid] : 0;
  s[tid] = v;
  __syncthreads();
  for (int off = 1; off < 256; off <<= 1) {
    int a = (tid >= off) ? s[tid - off] : 0;
    __syncthreads();
    s[tid] += a;
    __syncthreads();
  }
  if (tid < P) chunk_off[tid] = s[tid] - v;
}

__global__ __launch_bounds__(256) void ks3(int* __restrict__ cnt,
                                           const int* __restrict__ chunk_off, int M) {
  const int tid = threadIdx.x;
  const int t0 = blockIdx.x * 1024 + tid * 4;
  int v[4];
  int s = 0;
#pragma unroll
  for (int j = 0; j < 4; ++j) {
    v[j] = (t0 + j < M) ? cnt[t0 + j] : 0;
    s += v[j];
  }
  __shared__ int sh[256];
  sh[tid] = s;
  __syncthreads();
  for (int off = 1; off < 256; off <<= 1) {
    int a = (tid >= off) ? sh[tid - off] : 0;
    __syncthreads();
    sh[tid] += a;
    __syncthreads();
  }
  int excl = chunk_off[blockIdx.x] + sh[tid] - s;
#pragma unroll
  for (int j = 0; j < 4; ++j) {
    if (t0 + j < M) cnt[t0 + j] = excl;
    excl += v[j];
  }
}

// ---------------- CSR build pass 2: chunk scatter to bin regions --------------
__global__ __launch_bounds__(256) void k_cscat(const int* __restrict__ src,
                                               const int* __restrict__ dst,
                                               const int* __restrict__ S,
                                               unsigned* __restrict__ binrec,
                                               int E, int NB, int CHSZ) {
  __shared__ int cur[512];
  const int tid = threadIdx.x, c = blockIdx.x;
  for (int b = tid; b < NB; b += 256) cur[b] = S[(size_t)b * NCH + c];
  __syncthreads();
  const int beg = c * CHSZ, end = min(beg + CHSZ, E);
  for (int i = beg + tid; i < end; i += 256) {
    int d = dst[i];
    int pos = atomicAdd(&cur[d >> BSH], 1);
    binrec[pos] = ((unsigned)src[i] << BSH) | (unsigned)(d & (BDST - 1));
  }
}

// ---------------- CSR build pass 3: per-bin local sort, row[] + csr[] ---------
__global__ __launch_bounds__(256) void k_build(const unsigned* __restrict__ binrec,
                                               const int* __restrict__ S,
                                               int* __restrict__ row,
                                               int* __restrict__ csr,
                                               int n, int E, int NB) {
  __shared__ unsigned rec[CAP];
  __shared__ int hist[BDST], cur[BDST], sc[BDST];
  const int tid = threadIdx.x, b = blockIdx.x;
  const int base = S[(size_t)b * NCH];
  const int next = (b + 1 < NB) ? S[(size_t)(b + 1) * NCH] : E;
  const int cntb = next - base;
  if (tid < BDST) hist[tid] = 0;
  __syncthreads();
  for (int i = tid; i < cntb; i += 256) {
    unsigned r = binrec[base + i];
    if (i < CAP) rec[i] = r;
    atomicAdd(&hist[r & (BDST - 1)], 1);
  }
  __syncthreads();
  if (tid < BDST) sc[tid] = hist[tid];
  __syncthreads();
  for (int off = 1; off < BDST; off <<= 1) {
    int a = (tid < BDST && tid >= off) ? sc[tid - off] : 0;
    __syncthreads();
    if (tid < BDST) sc[tid] += a;
    __syncthreads();
  }
  if (tid < BDST) {
    int excl = sc[tid] - hist[tid];
    cur[tid] = excl;
    int v = b * BDST + tid;
    if (v < n) row[v] = base + excl;
  }
  if (b == NB - 1 && tid == 0) row[n] = E;
  __syncthreads();
  for (int i = tid; i < cntb; i += 256) {
    unsigned r = (i < CAP) ? rec[i] : binrec[base + i];
    int dl = r & (BDST - 1);
    int pos = base + atomicAdd(&cur[dl], 1);
    csr[pos] = (int)(r >> BSH);
  }
}

// ---------------- K6: single-pass weighted aggregation (paired-dword z) -------
__global__ __launch_bounds__(256) void k_agg(const unsigned* __restrict__ zd,
                                             const float* __restrict__ a_src,
                                             const float* __restrict__ a_dst,
                                             const int* __restrict__ row,
                                             const int* __restrict__ csr,
                                             float* __restrict__ out, int n) {
  const int lane = threadIdx.x & 63;
  const int grp = lane >> 4;
  const int sub = lane & 15;
  const int v = blockIdx.x * 4 + (threadIdx.x >> 6);
  if (v >= n) return;
  const int beg = row[v], end = row[v + 1];
  const float adv = a_dst[v];

  float accf[8];
#pragma unroll
  for (int j = 0; j < 8; ++j) accf[j] = 0.f;
  float ews = 0.f;

#pragma unroll 2
  for (int i = beg + grp; i < end; i += 4) {
    const int u = csr[i];
    const float a = a_src[u] + adv;
    const float e = a > 0.f ? a : 0.01f * a;
    const float ew = __expf(e);
    const uint4 zz = ((const uint4*)zd)[(size_t)u * 16 + sub];
    ews += ew;
    accf[0] += ew * __uint_as_float(zz.x << 16);
    accf[1] += ew * __uint_as_float(zz.x & 0xffff0000u);
    accf[2] += ew * __uint_as_float(zz.y << 16);
    accf[3] += ew * __uint_as_float(zz.y & 0xffff0000u);
    accf[4] += ew * __uint_as_float(zz.z << 16);
    accf[5] += ew * __uint_as_float(zz.z & 0xffff0000u);
    accf[6] += ew * __uint_as_float(zz.w << 16);
    accf[7] += ew * __uint_as_float(zz.w & 0xffff0000u);
  }

#pragma unroll
  for (int off = 16; off <= 32; off <<= 1) {
    ews += __shfl_xor(ews, off, 64);
#pragma unroll
    for (int j = 0; j < 8; ++j) accf[j] += __shfl_xor(accf[j], off, 64);
  }

  if (grp == 0) {
    const float inv = (end > beg) ? 1.f / ews : 0.f;
    float4 olo = make_float4(accf[0] * inv, accf[2] * inv, accf[4] * inv, accf[6] * inv);
    float4 ohi = make_float4(accf[1] * inv, accf[3] * inv, accf[5] * inv, accf[7] * inv);
    ((float4*)out)[(size_t)v * 32 + sub] = olo;
    ((float4*)out)[(size_t)v * 32 + 16 + sub] = ohi;
  }
}

extern "C" void kernel_launch(void* const* d_in, const int* in_sizes, int n_in,
                              void* d_out, int out_size, void* d_ws, size_t ws_size,
                              hipStream_t stream) {
  const float* h = (const float*)d_in[0];
  const float* emb = (const float*)d_in[1];
  const float* W = (const float*)d_in[2];
  const float* wfc = (const float*)d_in[3];
  const float* wemb = (const float*)d_in[4];
  const int* src = (const int*)d_in[5];
  const int* dst = (const int*)d_in[6];
  const int n = in_sizes[0] / D;
  const int E = in_sizes[5];
  const int NB = (n + BDST - 1) >> BSH;       // bins (391 for n=50000)
  const int CHSZ = (E + NCH - 1) / NCH;       // edges per chunk
  const int M = NB * NCH;                     // cnt matrix size
  const int G1 = (M + 1023) / 1024;           // scan tiles

  char* ws = (char*)d_ws;
  size_t off = 0;
  auto alloc = [&](size_t bytes) {
    void* p = ws + off;
    off = (off + bytes + 255) & ~(size_t)255;
    return p;
  };
  unsigned* zd = (unsigned*)alloc((size_t)n * 64 * 4);
  unsigned short* Wb = (unsigned short*)alloc(D * D * 2);
  float* sfc_s = (float*)alloc((size_t)n * 4);
  float* sfc_d = (float*)alloc((size_t)n * 4);
  float* a_src = (float*)alloc((size_t)n * 4);
  float* a_dst = (float*)alloc((size_t)n * 4);
  int* cnt = (int*)alloc((size_t)M * 4);
  int* partial = (int*)alloc((size_t)G1 * 4);
  int* chunk_off = (int*)alloc((size_t)G1 * 4);
  int* row = (int*)alloc((size_t)(n + 1) * 4);
  unsigned* binrec = (unsigned*)alloc((size_t)E * 4);
  int* csr = (int*)alloc((size_t)E * 4);
  (void)off;
  (void)ws_size;

  k_wconv<<<(D * D / 4 + 255) / 256, 256, 0, stream>>>(W, Wb);
  k_lin<<<(n + 63) / 64, 256, 0, stream>>>(h, Wb, wfc, zd, sfc_s, sfc_d, n);
  k_scal<<<(n + 3) / 4, 256, 0, stream>>>(emb, wemb, sfc_s, sfc_d, a_src, a_dst, n);
  k_chist<<<NCH, 256, 0, stream>>>(dst, cnt, E, NB, CHSZ);
  ks1<<<G1, 256, 0, stream>>>(cnt, partial, M);
  ks2<<<1, 256, 0, stream>>>(partial, chunk_off, G1);
  ks3<<<G1, 256, 0, stream>>>(cnt, chunk_off, M);
  k_cscat<<<NCH, 256, 0, stream>>>(src, dst, cnt, binrec, E, NB, CHSZ);
  k_build<<<NB, 256, 0, stream>>>(binrec, cnt, row, csr, n, E, NB);
  k_agg<<<(n + 3) / 4, 256, 0, stream>>>(zd, a_src, a_dst, row, csr, (float*)d_out, n);
}